// Round 1
// baseline (1019.262 us; speedup 1.0000x reference)
//
#include <hip/hip_runtime.h>
#include <math.h>

#define NPTS   100000
#define NRAYS  4096
#define NCHUNK 16
#define CSZ    6250        // NCHUNK * CSZ == NPTS
#define KTOP   10
#define KMER   12

static_assert(NCHUNK * CSZ == NPTS, "chunking must partition points exactly");

// ---------------------------------------------------------------------------
// Kernel 0: pack points as float4(x, y, z, -|x|^2) so the scan inner loop is
// minimal and wave-uniform-loadable (scalar loads).
// ---------------------------------------------------------------------------
__global__ __launch_bounds__(256) void prep_pts_kernel(const float* __restrict__ xyz,
                                                       float4* __restrict__ pts) {
    int i = blockIdx.x * 256 + threadIdx.x;
    if (i < NPTS) {
        float x = xyz[3 * i + 0];
        float y = xyz[3 * i + 1];
        float z = xyz[3 * i + 2];
        float xn = fmaf(x, x, fmaf(y, y, z * z));
        pts[i] = make_float4(x, y, z, -xn);
    }
}

// ---------------------------------------------------------------------------
// Kernel 1: each lane owns one ray; the wave scans a wave-uniform chunk of
// points (scalar loads broadcast point data). Per-lane register top-10 by
// score = 2*c.x - |x|^2  (max score == min distance). Branchless shift-insert
// guarded by a compare against the running 10th-best.
// ---------------------------------------------------------------------------
__global__ __launch_bounds__(64) void scan_kernel(const float* __restrict__ rays_o,
                                                  const float* __restrict__ rays_d,
                                                  const float4* __restrict__ pts,
                                                  float2* __restrict__ cand) {
    const int ray   = blockIdx.x * 64 + threadIdx.x;
    const int chunk = blockIdx.y;

    float ox = rays_o[3 * ray + 0], oy = rays_o[3 * ray + 1], oz = rays_o[3 * ray + 2];
    float dx = rays_d[3 * ray + 0], dy = rays_d[3 * ray + 1], dz = rays_d[3 * ray + 2];
    float cx, cy, cz;
    {
#pragma clang fp contract(off)
        // match numpy's unfused o + d*3.0
        cx = ox + dx * 3.0f;
        cy = oy + dy * 3.0f;
        cz = oz + dz * 3.0f;
    }

    float vs[KTOP];
    int   vi[KTOP];
#pragma unroll
    for (int j = 0; j < KTOP; ++j) { vs[j] = -INFINITY; vi[j] = 0x7fffffff; }

    const int base = chunk * CSZ;
#pragma unroll 4
    for (int j = 0; j < CSZ; ++j) {
        float4 p = pts[base + j];                       // wave-uniform -> s_load
        float dt = fmaf(cx, p.x, fmaf(cy, p.y, cz * p.z));
        float sc = fmaf(2.0f, dt, p.w);                 // 2*dot - |x|^2
        if (sc > vs[KTOP - 1]) {
            int id = base + j;
#pragma unroll
            for (int t = KTOP - 1; t >= 1; --t) {
                bool up   = sc > vs[t - 1];
                bool here = sc > vs[t];
                vs[t] = up ? vs[t - 1] : (here ? sc : vs[t]);
                vi[t] = up ? vi[t - 1] : (here ? id : vi[t]);
            }
            if (sc > vs[0]) { vs[0] = sc; vi[0] = id; }
        }
    }

    float2* out = cand + (ray * NCHUNK + chunk) * KTOP;
#pragma unroll
    for (int j = 0; j < KTOP; ++j) out[j] = make_float2(vs[j], __int_as_float(vi[j]));
}

// ---------------------------------------------------------------------------
// Kernel 2: per ray, merge 16 chunk lists (160 candidates) -> top-12 by f32
// score (idx tie-break), exact f64 re-rank -> final 10, then weights + rgb.
// ---------------------------------------------------------------------------
__device__ __forceinline__ float sigm(float x) { return 1.0f / (1.0f + expf(-x)); }

__global__ __launch_bounds__(64) void merge_kernel(const float* __restrict__ rays_o,
                                                   const float* __restrict__ rays_d,
                                                   const float2* __restrict__ cand,
                                                   const float* __restrict__ xyz,
                                                   const float* __restrict__ fdc,
                                                   const float* __restrict__ opac,
                                                   float* __restrict__ out) {
    const int ray = blockIdx.x * 64 + threadIdx.x;

    float vs[KMER];
    int   vi[KMER];
#pragma unroll
    for (int j = 0; j < KMER; ++j) { vs[j] = -INFINITY; vi[j] = 0x7fffffff; }

    auto ins = [&](float sc, int id) {
        bool beat = (sc > vs[KMER - 1]) || (sc == vs[KMER - 1] && id < vi[KMER - 1]);
        if (beat) {
#pragma unroll
            for (int t = KMER - 1; t >= 1; --t) {
                bool up   = (sc > vs[t - 1]) || (sc == vs[t - 1] && id < vi[t - 1]);
                bool here = (sc > vs[t])     || (sc == vs[t]     && id < vi[t]);
                vs[t] = up ? vs[t - 1] : (here ? sc : vs[t]);
                vi[t] = up ? vi[t - 1] : (here ? id : vi[t]);
            }
            bool top = (sc > vs[0]) || (sc == vs[0] && id < vi[0]);
            if (top) { vs[0] = sc; vi[0] = id; }
        }
    };

    const float4* c4 = (const float4*)(cand + ray * NCHUNK * KTOP);
    for (int j = 0; j < NCHUNK * KTOP / 2; ++j) {
        float4 e = c4[j];
        ins(e.x, __float_as_int(e.y));
        ins(e.z, __float_as_int(e.w));
    }

    // exact f64 re-rank of the 12 survivors
    float ox = rays_o[3 * ray + 0], oy = rays_o[3 * ray + 1], oz = rays_o[3 * ray + 2];
    float dx = rays_d[3 * ray + 0], dy = rays_d[3 * ray + 1], dz = rays_d[3 * ray + 2];
    float cxf, cyf, czf;
    {
#pragma clang fp contract(off)
        cxf = ox + dx * 3.0f;
        cyf = oy + dy * 3.0f;
        czf = oz + dz * 3.0f;
    }
    double Cx = (double)cxf, Cy = (double)cyf, Cz = (double)czf;
    double cn = Cx * Cx + Cy * Cy + Cz * Cz;

    double sq[KMER];
#pragma unroll
    for (int j = 0; j < KMER; ++j) {
        int id = vi[j];
        double X = (double)xyz[3 * id + 0];
        double Y = (double)xyz[3 * id + 1];
        double Z = (double)xyz[3 * id + 2];
        sq[j] = cn + (X * X + Y * Y + Z * Z) - 2.0 * (Cx * X + Cy * Y + Cz * Z);
    }

    // keep the 10 smallest (sq asc, idx asc)
    double bs[KTOP];
    int    bi[KTOP];
#pragma unroll
    for (int j = 0; j < KTOP; ++j) { bs[j] = INFINITY; bi[j] = 0x7fffffff; }
#pragma unroll
    for (int j = 0; j < KMER; ++j) {
        double s = sq[j];
        int    id = vi[j];
        bool beat = (s < bs[KTOP - 1]) || (s == bs[KTOP - 1] && id < bi[KTOP - 1]);
        if (beat) {
#pragma unroll
            for (int t = KTOP - 1; t >= 1; --t) {
                bool up   = (s < bs[t - 1]) || (s == bs[t - 1] && id < bi[t - 1]);
                bool here = (s < bs[t])     || (s == bs[t]     && id < bi[t]);
                bs[t] = up ? bs[t - 1] : (here ? s : bs[t]);
                bi[t] = up ? bi[t - 1] : (here ? id : bi[t]);
            }
            bool top = (s < bs[0]) || (s == bs[0] && id < bi[0]);
            if (top) { bs[0] = s; bi[0] = id; }
        }
    }

    // weights + rgb
    float wsum = 0.0f, r = 0.0f, g = 0.0f, b = 0.0f;
#pragma unroll
    for (int j = 0; j < KTOP; ++j) {
        int id = bi[j];
        float d = sqrtf(fmaxf((float)bs[j], 0.0f));
        float w = expf(-0.1f * d) * sigm(opac[id]);
        wsum += w;
        r += w * sigm(fdc[3 * id + 0]);
        g += w * sigm(fdc[3 * id + 1]);
        b += w * sigm(fdc[3 * id + 2]);
    }
    float inv = 1.0f / (wsum + 1e-8f);
    out[3 * ray + 0] = r * inv;
    out[3 * ray + 1] = g * inv;
    out[3 * ray + 2] = b * inv;
}

// ---------------------------------------------------------------------------
extern "C" void kernel_launch(void* const* d_in, const int* in_sizes, int n_in,
                              void* d_out, int out_size, void* d_ws, size_t ws_size,
                              hipStream_t stream) {
    const float* rays_o = (const float*)d_in[0];
    const float* rays_d = (const float*)d_in[1];
    const float* xyz    = (const float*)d_in[2];
    const float* fdc    = (const float*)d_in[3];
    const float* opac   = (const float*)d_in[4];
    float* out = (float*)d_out;

    // ws layout: [0, NPTS*16) packed points; then candidate lists
    float4* pts  = (float4*)d_ws;
    float2* cand = (float2*)((char*)d_ws + (size_t)NPTS * sizeof(float4));

    prep_pts_kernel<<<(NPTS + 255) / 256, 256, 0, stream>>>(xyz, pts);
    scan_kernel<<<dim3(NRAYS / 64, NCHUNK), 64, 0, stream>>>(rays_o, rays_d, pts, cand);
    merge_kernel<<<NRAYS / 64, 64, 0, stream>>>(rays_o, rays_d, cand, xyz, fdc, opac, out);
}

// Round 2
// 888.368 us; speedup vs baseline: 1.1473x; 1.1473x over previous
//
#include <hip/hip_runtime.h>
#include <math.h>

#define NPTS   100000
#define NRAYS  4096
#define NCHUNK 16
#define CSZ    6250        // NCHUNK * CSZ == NPTS
#define KTOP   10
#define KMER   12

// theta sample pass: 32 parts of 1568 pts = first 50176 points, 16 sub-blocks of 2 parts
#define NPART  32
#define APART  1568
#define AG     16
#define ANG    98          // 98*16 = 1568

// scan pipeline: groups of 20, 312 groups = 6240, tail 10
#define BG     20
#define BNG    312
#define BTAIL  6240

static_assert(NCHUNK * CSZ == NPTS, "chunk partition");
static_assert(AG * ANG == APART, "A part partition");
static_assert(BG * BNG == BTAIL && BTAIL < CSZ, "B group partition");

__device__ __forceinline__ void ray_center(const float* __restrict__ ro,
                                           const float* __restrict__ rd,
                                           int ray, float& cx, float& cy, float& cz) {
    float ox = ro[3 * ray + 0], oy = ro[3 * ray + 1], oz = ro[3 * ray + 2];
    float dx = rd[3 * ray + 0], dy = rd[3 * ray + 1], dz = rd[3 * ray + 2];
    {
#pragma clang fp contract(off)
        cx = ox + dx * 3.0f;
        cy = oy + dy * 3.0f;
        cz = oz + dz * 3.0f;
    }
}

// ---------------------------------------------------------------------------
// Kernel 0: pts = (x, y, z, -0.5*|x|^2); score = c.x - 0.5|x|^2 is monotone
// in -distance (3 FMA per point).
// ---------------------------------------------------------------------------
__global__ __launch_bounds__(256) void prep_pts_kernel(const float* __restrict__ xyz,
                                                       float4* __restrict__ pts) {
    int i = blockIdx.x * 256 + threadIdx.x;
    if (i < NPTS) {
        float x = xyz[3 * i + 0];
        float y = xyz[3 * i + 1];
        float z = xyz[3 * i + 2];
        pts[i] = make_float4(x, y, z, -0.5f * fmaf(x, x, fmaf(y, y, z * z)));
    }
}

// ---------------------------------------------------------------------------
// Kernel 1: branchless per-(ray, part) running max over 1568 sample points.
// Double-buffered register groups so loads pipeline ahead of the FMA chain.
// ---------------------------------------------------------------------------
__global__ __launch_bounds__(64) void theta_part_kernel(const float* __restrict__ ro,
                                                        const float* __restrict__ rd,
                                                        const float4* __restrict__ pts,
                                                        float* __restrict__ pm) {
    const int ray  = blockIdx.x * 64 + threadIdx.x;
    const int part = blockIdx.y;
    float cx, cy, cz;
    ray_center(ro, rd, ray, cx, cy, cz);

    const float4* __restrict__ P = pts + part * APART;
    float4 b0[AG], b1[AG];
    float m = -INFINITY;

#pragma unroll
    for (int u = 0; u < AG; ++u) b0[u] = P[u];

    for (int g = 0; g < ANG; g += 2) {
        const float4* Pa = P + (g + 1) * AG;
#pragma unroll
        for (int u = 0; u < AG; ++u) b1[u] = Pa[u];
#pragma unroll
        for (int u = 0; u < AG; ++u) {
            float4 p = b0[u];
            float t = fmaf(p.z, cz, p.w); t = fmaf(p.y, cy, t); t = fmaf(p.x, cx, t);
            m = fmaxf(m, t);
        }
        if (g + 2 < ANG) {
            const float4* Pb = P + (g + 2) * AG;
#pragma unroll
            for (int u = 0; u < AG; ++u) b0[u] = Pb[u];
        }
#pragma unroll
        for (int u = 0; u < AG; ++u) {
            float4 p = b1[u];
            float t = fmaf(p.z, cz, p.w); t = fmaf(p.y, cy, t); t = fmaf(p.x, cx, t);
            m = fmaxf(m, t);
        }
    }
    pm[part * NRAYS + ray] = m;   // coalesced
}

// ---------------------------------------------------------------------------
// Kernel 2: theta[ray] = 10th-largest of the 16 sub-block maxima. Guarantees
// >=10 distinct points with score >= theta, so scan may drop score < theta.
// ---------------------------------------------------------------------------
__global__ __launch_bounds__(64) void theta_reduce_kernel(const float* __restrict__ pm,
                                                          float* __restrict__ theta) {
    const int ray = blockIdx.x * 64 + threadIdx.x;
    float vs[KTOP];
#pragma unroll
    for (int j = 0; j < KTOP; ++j) vs[j] = -INFINITY;
#pragma unroll
    for (int b = 0; b < 16; ++b) {
        float m = fmaxf(pm[(2 * b) * NRAYS + ray], pm[(2 * b + 1) * NRAYS + ray]);
        if (m > vs[KTOP - 1]) {
#pragma unroll
            for (int s = KTOP - 1; s >= 1; --s) {
                bool up = m > vs[s - 1], here = m > vs[s];
                vs[s] = up ? vs[s - 1] : (here ? m : vs[s]);
            }
            if (m > vs[0]) vs[0] = m;
        }
    }
    theta[ray] = vs[KTOP - 1];
}

// ---------------------------------------------------------------------------
// Kernel 3: theta-guarded chunk scan. Per-lane top-10 of {chunk & score>=theta}
// (dropping <theta is exact; dropping 11th-in-chunk is exact). Software-
// pipelined 20-point register groups hide L2 latency at 1 wave/SIMD.
// ---------------------------------------------------------------------------
__global__ __launch_bounds__(64) void scan_kernel(const float* __restrict__ ro,
                                                  const float* __restrict__ rd,
                                                  const float4* __restrict__ pts,
                                                  const float* __restrict__ theta,
                                                  float2* __restrict__ cand) {
    const int ray   = blockIdx.x * 64 + threadIdx.x;
    const int chunk = blockIdx.y;
    float cx, cy, cz;
    ray_center(ro, rd, ray, cx, cy, cz);
    const float th = theta[ray];

    float vs[KTOP];
    int   vi[KTOP];
#pragma unroll
    for (int j = 0; j < KTOP; ++j) { vs[j] = -INFINITY; vi[j] = 0x7fffffff; }
    float guardv = th;   // = max(th, vs[9])

    const int base = chunk * CSZ;
    const float4* __restrict__ P = pts + base;

    float4 b0[BG], b1[BG];
#pragma unroll
    for (int u = 0; u < BG; ++u) b0[u] = P[u];

    auto proc = [&](const float4* b, int idx0) {
#pragma unroll
        for (int u = 0; u < BG; ++u) {
            float4 p = b[u];
            float t = fmaf(p.z, cz, p.w); t = fmaf(p.y, cy, t); t = fmaf(p.x, cx, t);
            if (t >= guardv) {                       // rare: ~2% of points per wave
                int id = idx0 + u;
#pragma unroll
                for (int s = KTOP - 1; s >= 1; --s) {
                    bool up = t > vs[s - 1], here = t > vs[s];
                    vs[s] = up ? vs[s - 1] : (here ? t : vs[s]);
                    vi[s] = up ? vi[s - 1] : (here ? id : vi[s]);
                }
                if (t > vs[0]) { vs[0] = t; vi[0] = id; }
                guardv = fmaxf(th, vs[KTOP - 1]);
            }
        }
    };

    for (int g = 0; g < BNG; g += 2) {
        const float4* Pa = P + (g + 1) * BG;
#pragma unroll
        for (int u = 0; u < BG; ++u) b1[u] = Pa[u];     // prefetch g+1
        proc(b0, base + g * BG);
        if (g + 2 < BNG) {
            const float4* Pb = P + (g + 2) * BG;
#pragma unroll
            for (int u = 0; u < BG; ++u) b0[u] = Pb[u]; // prefetch g+2
        }
        proc(b1, base + (g + 1) * BG);
    }
    // tail: points [6240, 6250)
#pragma unroll
    for (int j = BTAIL; j < CSZ; ++j) {
        float4 p = P[j];
        float t = fmaf(p.z, cz, p.w); t = fmaf(p.y, cy, t); t = fmaf(p.x, cx, t);
        if (t >= guardv) {
            int id = base + j;
#pragma unroll
            for (int s = KTOP - 1; s >= 1; --s) {
                bool up = t > vs[s - 1], here = t > vs[s];
                vs[s] = up ? vs[s - 1] : (here ? t : vs[s]);
                vi[s] = up ? vi[s - 1] : (here ? id : vi[s]);
            }
            if (t > vs[0]) { vs[0] = t; vi[0] = id; }
            guardv = fmaxf(th, vs[KTOP - 1]);
        }
    }

#pragma unroll
    for (int j = 0; j < KTOP; ++j)
        cand[(chunk * KTOP + j) * NRAYS + ray] = make_float2(vs[j], __int_as_float(vi[j]));
}

// ---------------------------------------------------------------------------
// Kernel 4: merge 160 candidates/ray (coalesced [slot][ray] layout) -> top-12
// by f32 score (idx tie-break) -> exact f64 re-rank -> final 10 -> rgb.
// ---------------------------------------------------------------------------
__device__ __forceinline__ float sigm(float x) { return 1.0f / (1.0f + expf(-x)); }

__global__ __launch_bounds__(64) void merge_kernel(const float* __restrict__ ro,
                                                   const float* __restrict__ rd,
                                                   const float2* __restrict__ cand,
                                                   const float* __restrict__ xyz,
                                                   const float* __restrict__ fdc,
                                                   const float* __restrict__ opac,
                                                   float* __restrict__ out) {
    const int ray = blockIdx.x * 64 + threadIdx.x;

    float vs[KMER];
    int   vi[KMER];
#pragma unroll
    for (int j = 0; j < KMER; ++j) { vs[j] = -INFINITY; vi[j] = 0x7fffffff; }

    auto ins = [&](float sc, int id) {
        bool beat = (sc > vs[KMER - 1]) || (sc == vs[KMER - 1] && id < vi[KMER - 1]);
        if (beat) {
#pragma unroll
            for (int t = KMER - 1; t >= 1; --t) {
                bool up   = (sc > vs[t - 1]) || (sc == vs[t - 1] && id < vi[t - 1]);
                bool here = (sc > vs[t])     || (sc == vs[t]     && id < vi[t]);
                vs[t] = up ? vs[t - 1] : (here ? sc : vs[t]);
                vi[t] = up ? vi[t - 1] : (here ? id : vi[t]);
            }
            bool top = (sc > vs[0]) || (sc == vs[0] && id < vi[0]);
            if (top) { vs[0] = sc; vi[0] = id; }
        }
    };

    const int NT = NCHUNK * KTOP;   // 160
    const int MG = 16;
    float2 c0[MG], c1[MG];
#pragma unroll
    for (int u = 0; u < MG; ++u) c0[u] = cand[u * NRAYS + ray];
    for (int g = 0; g < NT / MG; g += 2) {
#pragma unroll
        for (int u = 0; u < MG; ++u) c1[u] = cand[((g + 1) * MG + u) * NRAYS + ray];
#pragma unroll
        for (int u = 0; u < MG; ++u) ins(c0[u].x, __float_as_int(c0[u].y));
        if (g + 2 < NT / MG) {
#pragma unroll
            for (int u = 0; u < MG; ++u) c0[u] = cand[((g + 2) * MG + u) * NRAYS + ray];
        }
#pragma unroll
        for (int u = 0; u < MG; ++u) ins(c1[u].x, __float_as_int(c1[u].y));
    }

    // exact f64 re-rank of the 12 survivors (invalid slots -> +inf)
    float cxf, cyf, czf;
    ray_center(ro, rd, ray, cxf, cyf, czf);
    double Cx = (double)cxf, Cy = (double)cyf, Cz = (double)czf;
    double cn = Cx * Cx + Cy * Cy + Cz * Cz;

    double sq[KMER];
#pragma unroll
    for (int j = 0; j < KMER; ++j) {
        int id = vi[j];
        bool valid = (id != 0x7fffffff);
        int idc = valid ? id : 0;
        double X = (double)xyz[3 * idc + 0];
        double Y = (double)xyz[3 * idc + 1];
        double Z = (double)xyz[3 * idc + 2];
        double v = cn + (X * X + Y * Y + Z * Z) - 2.0 * (Cx * X + Cy * Y + Cz * Z);
        sq[j] = valid ? v : (double)INFINITY;
    }

    double bs[KTOP];
    int    bi[KTOP];
#pragma unroll
    for (int j = 0; j < KTOP; ++j) { bs[j] = INFINITY; bi[j] = 0x7fffffff; }
#pragma unroll
    for (int j = 0; j < KMER; ++j) {
        double s = sq[j];
        int    id = vi[j];
        bool beat = (s < bs[KTOP - 1]) || (s == bs[KTOP - 1] && id < bi[KTOP - 1]);
        if (beat) {
#pragma unroll
            for (int t = KTOP - 1; t >= 1; --t) {
                bool up   = (s < bs[t - 1]) || (s == bs[t - 1] && id < bi[t - 1]);
                bool here = (s < bs[t])     || (s == bs[t]     && id < bi[t]);
                bs[t] = up ? bs[t - 1] : (here ? s : bs[t]);
                bi[t] = up ? bi[t - 1] : (here ? id : bi[t]);
            }
            bool top = (s < bs[0]) || (s == bs[0] && id < bi[0]);
            if (top) { bs[0] = s; bi[0] = id; }
        }
    }

    float wsum = 0.0f, r = 0.0f, g2 = 0.0f, b2 = 0.0f;
#pragma unroll
    for (int j = 0; j < KTOP; ++j) {
        int id = bi[j];
        float d = sqrtf(fmaxf((float)bs[j], 0.0f));
        float w = expf(-0.1f * d) * sigm(opac[id]);
        wsum += w;
        r  += w * sigm(fdc[3 * id + 0]);
        g2 += w * sigm(fdc[3 * id + 1]);
        b2 += w * sigm(fdc[3 * id + 2]);
    }
    float inv = 1.0f / (wsum + 1e-8f);
    out[3 * ray + 0] = r  * inv;
    out[3 * ray + 1] = g2 * inv;
    out[3 * ray + 2] = b2 * inv;
}

// ---------------------------------------------------------------------------
extern "C" void kernel_launch(void* const* d_in, const int* in_sizes, int n_in,
                              void* d_out, int out_size, void* d_ws, size_t ws_size,
                              hipStream_t stream) {
    const float* rays_o = (const float*)d_in[0];
    const float* rays_d = (const float*)d_in[1];
    const float* xyz    = (const float*)d_in[2];
    const float* fdc    = (const float*)d_in[3];
    const float* opac   = (const float*)d_in[4];
    float* out = (float*)d_out;

    // ws: [0, 1.6MB) pts ; [1.6MB, 6.84MB) cand (partmax aliases its head).
    // theta lives in d_out[0:4096] (merge_kernel overwrites d_out last).
    float4* pts  = (float4*)d_ws;
    float*  pm   = (float*)((char*)d_ws + (size_t)NPTS * sizeof(float4));
    float2* cand = (float2*)((char*)d_ws + (size_t)NPTS * sizeof(float4));
    float*  theta = (float*)d_out;

    prep_pts_kernel<<<(NPTS + 255) / 256, 256, 0, stream>>>(xyz, pts);
    theta_part_kernel<<<dim3(NRAYS / 64, NPART), 64, 0, stream>>>(rays_o, rays_d, pts, pm);
    theta_reduce_kernel<<<NRAYS / 64, 64, 0, stream>>>(pm, theta);
    scan_kernel<<<dim3(NRAYS / 64, NCHUNK), 64, 0, stream>>>(rays_o, rays_d, pts, theta, cand);
    merge_kernel<<<NRAYS / 64, 64, 0, stream>>>(rays_o, rays_d, cand, xyz, fdc, opac, out);
}

// Round 3
// 278.745 us; speedup vs baseline: 3.6566x; 3.1870x over previous
//
#include <hip/hip_runtime.h>
#include <math.h>

#define NPTS   100000
#define NRAYS  4096
#define KTOP   10
#define KMER   12

#define P      8            // float4 points per lane (512 per wave)
#define PBLK   49           // point blocks of 2048 -> 100352 padded points
#define NPAD   (PBLK * 2048)
#define TBLK   24           // theta sample: first 24 blocks = 49152 points
#define NPART  (TBLK * 4)   // 96 parts (one per wave of 512 points)
#define RC     32           // ray chunks -> 128 rays per block
#define RPB    (NRAYS / RC) // 128
#define CAP    128          // candidate slots per ray

static_assert(RC * RPB == NRAYS, "ray partition");

// ---------------------------------------------------------------------------
// prep: pts = (x,y,z,-0.5|x|^2), padded tail scores -inf; raycen = centers.
// ---------------------------------------------------------------------------
__global__ __launch_bounds__(256) void prep_pts_kernel(const float* __restrict__ xyz,
                                                       float4* __restrict__ pts) {
    int i = blockIdx.x * 256 + threadIdx.x;
    if (i >= NPAD) return;
    if (i < NPTS) {
        float x = xyz[3 * i + 0];
        float y = xyz[3 * i + 1];
        float z = xyz[3 * i + 2];
        pts[i] = make_float4(x, y, z, -0.5f * fmaf(x, x, fmaf(y, y, z * z)));
    } else {
        pts[i] = make_float4(0.0f, 0.0f, 0.0f, -INFINITY);
    }
}

__global__ __launch_bounds__(256) void prep_rays_kernel(const float* __restrict__ ro,
                                                        const float* __restrict__ rd,
                                                        float4* __restrict__ raycen) {
    int ray = blockIdx.x * 256 + threadIdx.x;
    if (ray >= NRAYS) return;
    float ox = ro[3 * ray + 0], oy = ro[3 * ray + 1], oz = ro[3 * ray + 2];
    float dx = rd[3 * ray + 0], dy = rd[3 * ray + 1], dz = rd[3 * ray + 2];
    float cx, cy, cz;
    {
#pragma clang fp contract(off)
        cx = ox + dx * 3.0f;
        cy = oy + dy * 3.0f;
        cz = oz + dz * 3.0f;
    }
    raycen[ray] = make_float4(cx, cy, cz, 0.0f);
}

// ---------------------------------------------------------------------------
// theta part maxima: points in VGPRs (512/wave = 1 part), stream rays via
// s_load; per (wave,ray) butterfly-max -> pm[part][ray].
// ---------------------------------------------------------------------------
__global__ __launch_bounds__(256) void theta_part_kernel(const float4* __restrict__ pts,
                                                         const float4* __restrict__ raycen,
                                                         float* __restrict__ pm) {
    const int pblk = blockIdx.x;            // 0..TBLK-1
    const int rchunk = blockIdx.y;          // 0..RC-1
    const int wave = threadIdx.x >> 6;
    const int lane = threadIdx.x & 63;
    const int part = pblk * 4 + wave;
    const int id0 = pblk * 2048 + wave * 512 + lane;

    float4 b[P];
#pragma unroll
    for (int u = 0; u < P; ++u) b[u] = pts[id0 + u * 64];

    const int rbase = rchunk * RPB;
    float4 rp = raycen[rbase];
    for (int r = 0; r < RPB; ++r) {
        float4 rpn = raycen[rbase + r + 1];          // padded +1
        float m = -INFINITY;
#pragma unroll
        for (int u = 0; u < P; ++u) {
            float t = fmaf(b[u].z, rp.z, b[u].w);
            t = fmaf(b[u].y, rp.y, t);
            t = fmaf(b[u].x, rp.x, t);
            m = fmaxf(m, t);
        }
#pragma unroll
        for (int off = 1; off < 64; off <<= 1) m = fmaxf(m, __shfl_xor(m, off));
        if (lane == 0) pm[part * NRAYS + rbase + r] = m;
        rp = rpn;
    }
}

// ---------------------------------------------------------------------------
// theta reduce: theta[ray] = 10th-largest of 96 part maxima (>=10 distinct
// points with score >= theta). Packs raypack=(cx,cy,cz,theta); zeroes cnt.
// ---------------------------------------------------------------------------
__global__ __launch_bounds__(64) void theta_reduce_kernel(const float* __restrict__ pm,
                                                          const float4* __restrict__ raycen,
                                                          float4* __restrict__ raypack,
                                                          int* __restrict__ cnt) {
    const int ray = blockIdx.x * 64 + threadIdx.x;
    float vs[KTOP];
#pragma unroll
    for (int j = 0; j < KTOP; ++j) vs[j] = -INFINITY;
    for (int p = 0; p < NPART; ++p) {
        float m = pm[p * NRAYS + ray];               // coalesced
        if (m > vs[KTOP - 1]) {
#pragma unroll
            for (int s = KTOP - 1; s >= 1; --s) {
                bool up = m > vs[s - 1], here = m > vs[s];
                vs[s] = up ? vs[s - 1] : (here ? m : vs[s]);
            }
            if (m > vs[0]) vs[0] = m;
        }
    }
    float4 c = raycen[ray];
    raypack[ray] = make_float4(c.x, c.y, c.z, vs[KTOP - 1]);
    cnt[ray] = 0;
}

// ---------------------------------------------------------------------------
// scan: points in VGPRs, stream rays; emit ALL points with score >= theta
// (exact: theta guarantees the true top-10 all pass). Ballot-guarded rare
// emit path with atomic slot append.
// ---------------------------------------------------------------------------
__global__ __launch_bounds__(256) void scan_kernel(const float4* __restrict__ pts,
                                                   const float4* __restrict__ raypack,
                                                   int* __restrict__ cnt,
                                                   float2* __restrict__ cand) {
    const int pblk = blockIdx.x;            // 0..PBLK-1
    const int rchunk = blockIdx.y;          // 0..RC-1
    const int wave = threadIdx.x >> 6;
    const int lane = threadIdx.x & 63;
    const int id0 = pblk * 2048 + wave * 512 + lane;

    float4 b[P];
#pragma unroll
    for (int u = 0; u < P; ++u) b[u] = pts[id0 + u * 64];

    const int rbase = rchunk * RPB;
    float4 rp = raypack[rbase];
    for (int r = 0; r < RPB; ++r) {
        float4 rpn = raypack[rbase + r + 1];         // padded +1
        const float th = rp.w;
        float s[P];
        float hm = -INFINITY;
#pragma unroll
        for (int u = 0; u < P; ++u) {
            float t = fmaf(b[u].z, rp.z, b[u].w);
            t = fmaf(b[u].y, rp.y, t);
            t = fmaf(b[u].x, rp.x, t);
            s[u] = t;
            hm = fmaxf(hm, t);
        }
        if (__ballot(hm >= th)) {                    // wave-uniform rare branch
            const int rayid = rbase + r;
#pragma unroll
            for (int u = 0; u < P; ++u) {
                if (s[u] >= th) {
                    int slot = atomicAdd(&cnt[rayid], 1);
                    if (slot < CAP)
                        cand[(rayid << 7) + slot] =
                            make_float2(s[u], __int_as_float(id0 + u * 64));
                }
            }
        }
        rp = rpn;
    }
}

// ---------------------------------------------------------------------------
// merge: per ray, top-12 by f32 score (idx tie-break) over its candidate
// list, exact f64 re-rank -> final 10 -> weights + rgb. (Proven epilogue.)
// ---------------------------------------------------------------------------
__device__ __forceinline__ float sigm(float x) { return 1.0f / (1.0f + expf(-x)); }

__global__ __launch_bounds__(64) void merge_kernel(const float* __restrict__ ro,
                                                   const float* __restrict__ rd,
                                                   const int* __restrict__ cnt,
                                                   const float2* __restrict__ cand,
                                                   const float* __restrict__ xyz,
                                                   const float* __restrict__ fdc,
                                                   const float* __restrict__ opac,
                                                   float* __restrict__ out) {
    const int ray = blockIdx.x * 64 + threadIdx.x;
    int n = cnt[ray];
    n = n < CAP ? n : CAP;
    int nm = n;
#pragma unroll
    for (int off = 1; off < 64; off <<= 1) {
        int o = __shfl_xor(nm, off);
        nm = nm > o ? nm : o;
    }

    float vs[KMER];
    int   vi[KMER];
#pragma unroll
    for (int j = 0; j < KMER; ++j) { vs[j] = -INFINITY; vi[j] = 0x7fffffff; }

    const float2* cl = cand + (ray << 7);
    for (int j = 0; j < nm; ++j) {
        if (j < n) {
            float2 e = cl[j];
            float sc = e.x;
            int   id = __float_as_int(e.y);
            bool beat = (sc > vs[KMER - 1]) || (sc == vs[KMER - 1] && id < vi[KMER - 1]);
            if (beat) {
#pragma unroll
                for (int t = KMER - 1; t >= 1; --t) {
                    bool up   = (sc > vs[t - 1]) || (sc == vs[t - 1] && id < vi[t - 1]);
                    bool here = (sc > vs[t])     || (sc == vs[t]     && id < vi[t]);
                    vs[t] = up ? vs[t - 1] : (here ? sc : vs[t]);
                    vi[t] = up ? vi[t - 1] : (here ? id : vi[t]);
                }
                bool top = (sc > vs[0]) || (sc == vs[0] && id < vi[0]);
                if (top) { vs[0] = sc; vi[0] = id; }
            }
        }
    }

    // exact f64 re-rank of the survivors (invalid slots -> +inf)
    float ox = ro[3 * ray + 0], oy = ro[3 * ray + 1], oz = ro[3 * ray + 2];
    float dx = rd[3 * ray + 0], dy = rd[3 * ray + 1], dz = rd[3 * ray + 2];
    float cxf, cyf, czf;
    {
#pragma clang fp contract(off)
        cxf = ox + dx * 3.0f;
        cyf = oy + dy * 3.0f;
        czf = oz + dz * 3.0f;
    }
    double Cx = (double)cxf, Cy = (double)cyf, Cz = (double)czf;
    double cn = Cx * Cx + Cy * Cy + Cz * Cz;

    double sq[KMER];
#pragma unroll
    for (int j = 0; j < KMER; ++j) {
        int id = vi[j];
        bool valid = (id != 0x7fffffff);
        int idc = valid ? id : 0;
        double X = (double)xyz[3 * idc + 0];
        double Y = (double)xyz[3 * idc + 1];
        double Z = (double)xyz[3 * idc + 2];
        double v = cn + (X * X + Y * Y + Z * Z) - 2.0 * (Cx * X + Cy * Y + Cz * Z);
        sq[j] = valid ? v : (double)INFINITY;
    }

    double bs[KTOP];
    int    bi[KTOP];
#pragma unroll
    for (int j = 0; j < KTOP; ++j) { bs[j] = INFINITY; bi[j] = 0x7fffffff; }
#pragma unroll
    for (int j = 0; j < KMER; ++j) {
        double sd = sq[j];
        int    id = vi[j];
        bool beat = (sd < bs[KTOP - 1]) || (sd == bs[KTOP - 1] && id < bi[KTOP - 1]);
        if (beat) {
#pragma unroll
            for (int t = KTOP - 1; t >= 1; --t) {
                bool up   = (sd < bs[t - 1]) || (sd == bs[t - 1] && id < bi[t - 1]);
                bool here = (sd < bs[t])     || (sd == bs[t]     && id < bi[t]);
                bs[t] = up ? bs[t - 1] : (here ? sd : bs[t]);
                bi[t] = up ? bi[t - 1] : (here ? id : bi[t]);
            }
            bool top = (sd < bs[0]) || (sd == bs[0] && id < bi[0]);
            if (top) { bs[0] = sd; bi[0] = id; }
        }
    }

    float wsum = 0.0f, r = 0.0f, g2 = 0.0f, b2 = 0.0f;
#pragma unroll
    for (int j = 0; j < KTOP; ++j) {
        int id = bi[j];
        float d = sqrtf(fmaxf((float)bs[j], 0.0f));
        float w = expf(-0.1f * d) * sigm(opac[id]);
        wsum += w;
        r  += w * sigm(fdc[3 * id + 0]);
        g2 += w * sigm(fdc[3 * id + 1]);
        b2 += w * sigm(fdc[3 * id + 2]);
    }
    float inv = 1.0f / (wsum + 1e-8f);
    out[3 * ray + 0] = r  * inv;
    out[3 * ray + 1] = g2 * inv;
    out[3 * ray + 2] = b2 * inv;
}

// ---------------------------------------------------------------------------
extern "C" void kernel_launch(void* const* d_in, const int* in_sizes, int n_in,
                              void* d_out, int out_size, void* d_ws, size_t ws_size,
                              hipStream_t stream) {
    const float* rays_o = (const float*)d_in[0];
    const float* rays_d = (const float*)d_in[1];
    const float* xyz    = (const float*)d_in[2];
    const float* fdc    = (const float*)d_in[3];
    const float* opac   = (const float*)d_in[4];
    float* out = (float*)d_out;

    // ws layout (pm aliases cand; pm dead after theta_reduce, cand written by
    // scan afterwards). Total ~5.95 MB (< 6.84 MB proven in rounds 1-2).
    char* w = (char*)d_ws;
    float4* pts     = (float4*)w;                           w += (size_t)NPAD * 16;
    float4* raycen  = (float4*)w;                           w += (size_t)(NRAYS + 1) * 16;
    float4* raypack = (float4*)w;                           w += (size_t)(NRAYS + 1) * 16;
    int*    cnt     = (int*)w;                              w += (size_t)NRAYS * 4;
    float*  pm      = (float*)w;
    float2* cand    = (float2*)w;

    prep_pts_kernel<<<NPAD / 256, 256, 0, stream>>>(xyz, pts);
    prep_rays_kernel<<<NRAYS / 256, 256, 0, stream>>>(rays_o, rays_d, raycen);
    theta_part_kernel<<<dim3(TBLK, RC), 256, 0, stream>>>(pts, raycen, pm);
    theta_reduce_kernel<<<NRAYS / 64, 64, 0, stream>>>(pm, raycen, raypack, cnt);
    scan_kernel<<<dim3(PBLK, RC), 256, 0, stream>>>(pts, raypack, cnt, cand);
    merge_kernel<<<NRAYS / 64, 64, 0, stream>>>(rays_o, rays_d, cnt, cand, xyz, fdc, opac, out);
}

// Round 4
// 244.368 us; speedup vs baseline: 4.1710x; 1.1407x over previous
//
#include <hip/hip_runtime.h>
#include <math.h>

#define NPTS   100000
#define NRAYS  4096
#define KTOP   10
#define KMER   12
#define CAP    128

// scan: 16 pts/lane, blocks of 256 = 4096 pts/block, 25 blocks = 102400 padded
#define PSC    16
#define SBLK   25
#define RCS    64                 // ray chunks for scan
#define RPBS   (NRAYS / RCS)      // 64 rays per scan block

// theta sample: 8 pts/lane, 24 blocks of 2048 = 49152 pts, 96 parts of 512
#define PTH    8
#define TBLK   24
#define NPART  (TBLK * 4)
#define RCT    32                 // ray chunks for theta
#define RPBT   (NRAYS / RCT)      // 128 rays per theta block

static_assert(SBLK * 4096 >= NPTS, "scan covers all points");
static_assert(TBLK * 2048 <= NPTS, "theta sample within real points");

__device__ __forceinline__ float4 make_center(const float* __restrict__ ro,
                                              const float* __restrict__ rd,
                                              int ray, float w) {
    float ox = ro[3 * ray + 0], oy = ro[3 * ray + 1], oz = ro[3 * ray + 2];
    float dx = rd[3 * ray + 0], dy = rd[3 * ray + 1], dz = rd[3 * ray + 2];
    float cx, cy, cz;
    {
#pragma clang fp contract(off)
        cx = ox + dx * 3.0f;
        cy = oy + dy * 3.0f;
        cz = oz + dz * 3.0f;
    }
    return make_float4(cx, cy, cz, w);
}

// ---------------------------------------------------------------------------
// theta_part: points in VGPRs (8/lane, part = wave's 512 pts), ray centers
// computed into LDS, 2-ray-interleaved butterfly max -> pm[part][ray].
// ---------------------------------------------------------------------------
__global__ __launch_bounds__(256) void theta_part_kernel(const float* __restrict__ xyz,
                                                         const float* __restrict__ ro,
                                                         const float* __restrict__ rd,
                                                         float* __restrict__ pm) {
    __shared__ float4 rsh[RPBT];
    const int pblk = blockIdx.x, rchunk = blockIdx.y;
    const int tid = threadIdx.x, wave = tid >> 6, lane = tid & 63;
    const int rbase = rchunk * RPBT;

    if (tid < RPBT) rsh[tid] = make_center(ro, rd, rbase + tid, 0.0f);

    const int id0 = pblk * 2048 + wave * 512 + lane;   // < 49152, all real
    float px[PTH], py[PTH], pz[PTH], pw[PTH];
#pragma unroll
    for (int u = 0; u < PTH; ++u) {
        int id = id0 + u * 64;
        float x = xyz[3 * id + 0], y = xyz[3 * id + 1], z = xyz[3 * id + 2];
        px[u] = x; py[u] = y; pz[u] = z;
        pw[u] = -0.5f * fmaf(x, x, fmaf(y, y, z * z));
    }
    __syncthreads();

    const int part = pblk * 4 + wave;
    for (int r = 0; r < RPBT; r += 2) {
        float4 r0 = rsh[r], r1 = rsh[r + 1];
        float m0 = -INFINITY, m1 = -INFINITY;
#pragma unroll
        for (int u = 0; u < PTH; ++u) {
            float t0 = fmaf(pz[u], r0.z, pw[u]);
            t0 = fmaf(py[u], r0.y, t0);
            t0 = fmaf(px[u], r0.x, t0);
            m0 = fmaxf(m0, t0);
            float t1 = fmaf(pz[u], r1.z, pw[u]);
            t1 = fmaf(py[u], r1.y, t1);
            t1 = fmaf(px[u], r1.x, t1);
            m1 = fmaxf(m1, t1);
        }
#pragma unroll
        for (int off = 1; off < 64; off <<= 1) {       // interleaved chains
            m0 = fmaxf(m0, __shfl_xor(m0, off));
            m1 = fmaxf(m1, __shfl_xor(m1, off));
        }
        if (lane == 0) {
            pm[part * NRAYS + rbase + r]     = m0;
            pm[part * NRAYS + rbase + r + 1] = m1;
        }
    }
}

// ---------------------------------------------------------------------------
// theta_reduce: theta[ray] = 10th-largest of 96 part maxima (guarantees >=10
// distinct points with score >= theta). Batched loads; zeroes cnt.
// ---------------------------------------------------------------------------
__global__ __launch_bounds__(256) void theta_reduce_kernel(const float* __restrict__ pm,
                                                           float* __restrict__ theta,
                                                           int* __restrict__ cnt) {
    const int ray = blockIdx.x * 256 + threadIdx.x;
    float vs[KTOP];
#pragma unroll
    for (int j = 0; j < KTOP; ++j) vs[j] = -INFINITY;
#pragma unroll 1
    for (int g = 0; g < NPART / 8; ++g) {
        float m[8];
#pragma unroll
        for (int j = 0; j < 8; ++j) m[j] = pm[(g * 8 + j) * NRAYS + ray];
#pragma unroll
        for (int j = 0; j < 8; ++j) {
            float v = m[j];
            if (v > vs[KTOP - 1]) {
#pragma unroll
                for (int s = KTOP - 1; s >= 1; --s) {
                    bool up = v > vs[s - 1], here = v > vs[s];
                    vs[s] = up ? vs[s - 1] : (here ? v : vs[s]);
                }
                if (v > vs[0]) vs[0] = v;
            }
        }
    }
    theta[ray] = vs[KTOP - 1];
    cnt[ray] = 0;
}

// ---------------------------------------------------------------------------
// scan: 16 pts/lane in VGPRs (xyz + score bias recomputed inline, padded tail
// = -inf), rays+theta staged in LDS, emit every point with score >= theta.
// ---------------------------------------------------------------------------
__global__ __launch_bounds__(256) void scan_kernel(const float* __restrict__ xyz,
                                                   const float* __restrict__ ro,
                                                   const float* __restrict__ rd,
                                                   const float* __restrict__ theta,
                                                   int* __restrict__ cnt,
                                                   float2* __restrict__ cand) {
    __shared__ float4 rsh[RPBS];
    const int pblk = blockIdx.x, rchunk = blockIdx.y;
    const int tid = threadIdx.x, wave = tid >> 6, lane = tid & 63;
    const int rbase = rchunk * RPBS;

    if (tid < RPBS) rsh[tid] = make_center(ro, rd, rbase + tid, theta[rbase + tid]);

    const int id0 = pblk * 4096 + wave * 1024 + lane;
    float px[PSC], py[PSC], pz[PSC], pw[PSC];
#pragma unroll
    for (int u = 0; u < PSC; ++u) {
        int id = id0 + u * 64;
        bool valid = (id < NPTS);
        int idc = valid ? id : 0;
        float x = xyz[3 * idc + 0], y = xyz[3 * idc + 1], z = xyz[3 * idc + 2];
        px[u] = x; py[u] = y; pz[u] = z;
        pw[u] = valid ? -0.5f * fmaf(x, x, fmaf(y, y, z * z)) : -INFINITY;
    }
    __syncthreads();

    float4 rp = rsh[0];
    for (int r = 0; r < RPBS; ++r) {
        float4 rpn = rsh[(r + 1) & (RPBS - 1)];        // prefetch (r=last wraps, unused)
        float s[PSC];
#pragma unroll
        for (int u = 0; u < PSC; ++u) {
            float t = fmaf(pz[u], rp.z, pw[u]);
            t = fmaf(py[u], rp.y, t);
            t = fmaf(px[u], rp.x, t);
            s[u] = t;
        }
        // max tree in triples -> v_max3
        float a0 = fmaxf(fmaxf(s[0], s[1]), s[2]);
        float a1 = fmaxf(fmaxf(s[3], s[4]), s[5]);
        float a2 = fmaxf(fmaxf(s[6], s[7]), s[8]);
        float a3 = fmaxf(fmaxf(s[9], s[10]), s[11]);
        float a4 = fmaxf(fmaxf(s[12], s[13]), s[14]);
        float b0 = fmaxf(fmaxf(a0, a1), a2);
        float b1 = fmaxf(fmaxf(a3, a4), s[15]);
        float hm = fmaxf(b0, b1);

        if (__ballot(hm >= rp.w)) {
            const int rayid = rbase + r;
#pragma unroll
            for (int u = 0; u < PSC; ++u) {
                if (s[u] >= rp.w) {
                    int slot = atomicAdd(&cnt[rayid], 1);
                    if (slot < CAP)
                        cand[(rayid << 7) + slot] =
                            make_float2(s[u], __int_as_float(id0 + u * 64));
                }
            }
        }
        rp = rpn;
    }
}

// ---------------------------------------------------------------------------
// merge: per ray top-12 by f32 score (idx tie-break), exact f64 re-rank ->
// final 10 -> weights + rgb. Batched candidate loads.
// ---------------------------------------------------------------------------
__device__ __forceinline__ float sigm(float x) { return 1.0f / (1.0f + expf(-x)); }

__global__ __launch_bounds__(256) void merge_kernel(const float* __restrict__ ro,
                                                    const float* __restrict__ rd,
                                                    const int* __restrict__ cnt,
                                                    const float2* __restrict__ cand,
                                                    const float* __restrict__ xyz,
                                                    const float* __restrict__ fdc,
                                                    const float* __restrict__ opac,
                                                    float* __restrict__ out) {
    const int ray = blockIdx.x * 256 + threadIdx.x;
    int n = cnt[ray];
    n = n < CAP ? n : CAP;
    int nm = n;
#pragma unroll
    for (int off = 1; off < 64; off <<= 1) {
        int o = __shfl_xor(nm, off);
        nm = nm > o ? nm : o;
    }

    float vs[KMER];
    int   vi[KMER];
#pragma unroll
    for (int j = 0; j < KMER; ++j) { vs[j] = -INFINITY; vi[j] = 0x7fffffff; }

    const float2* cl = cand + (ray << 7);
#pragma unroll 1
    for (int j0 = 0; j0 < nm; j0 += 8) {
        float2 e[8];
#pragma unroll
        for (int j = 0; j < 8; ++j) {
            int idx = j0 + j;
            e[j] = cl[idx < CAP ? idx : CAP - 1];      // always-valid address
        }
#pragma unroll
        for (int j = 0; j < 8; ++j) {
            if (j0 + j < n) {
                float sc = e[j].x;
                int   id = __float_as_int(e[j].y);
                bool beat = (sc > vs[KMER - 1]) || (sc == vs[KMER - 1] && id < vi[KMER - 1]);
                if (beat) {
#pragma unroll
                    for (int t = KMER - 1; t >= 1; --t) {
                        bool up   = (sc > vs[t - 1]) || (sc == vs[t - 1] && id < vi[t - 1]);
                        bool here = (sc > vs[t])     || (sc == vs[t]     && id < vi[t]);
                        vs[t] = up ? vs[t - 1] : (here ? sc : vs[t]);
                        vi[t] = up ? vi[t - 1] : (here ? id : vi[t]);
                    }
                    bool top = (sc > vs[0]) || (sc == vs[0] && id < vi[0]);
                    if (top) { vs[0] = sc; vi[0] = id; }
                }
            }
        }
    }

    // exact f64 re-rank of the 12 survivors (invalid slots -> +inf)
    float ox = ro[3 * ray + 0], oy = ro[3 * ray + 1], oz = ro[3 * ray + 2];
    float dx = rd[3 * ray + 0], dy = rd[3 * ray + 1], dz = rd[3 * ray + 2];
    float cxf, cyf, czf;
    {
#pragma clang fp contract(off)
        cxf = ox + dx * 3.0f;
        cyf = oy + dy * 3.0f;
        czf = oz + dz * 3.0f;
    }
    double Cx = (double)cxf, Cy = (double)cyf, Cz = (double)czf;
    double cn = Cx * Cx + Cy * Cy + Cz * Cz;

    double sq[KMER];
#pragma unroll
    for (int j = 0; j < KMER; ++j) {
        int id = vi[j];
        bool valid = (id != 0x7fffffff);
        int idc = valid ? id : 0;
        double X = (double)xyz[3 * idc + 0];
        double Y = (double)xyz[3 * idc + 1];
        double Z = (double)xyz[3 * idc + 2];
        double v = cn + (X * X + Y * Y + Z * Z) - 2.0 * (Cx * X + Cy * Y + Cz * Z);
        sq[j] = valid ? v : (double)INFINITY;
    }

    double bs[KTOP];
    int    bi[KTOP];
#pragma unroll
    for (int j = 0; j < KTOP; ++j) { bs[j] = INFINITY; bi[j] = 0x7fffffff; }
#pragma unroll
    for (int j = 0; j < KMER; ++j) {
        double sd = sq[j];
        int    id = vi[j];
        bool beat = (sd < bs[KTOP - 1]) || (sd == bs[KTOP - 1] && id < bi[KTOP - 1]);
        if (beat) {
#pragma unroll
            for (int t = KTOP - 1; t >= 1; --t) {
                bool up   = (sd < bs[t - 1]) || (sd == bs[t - 1] && id < bi[t - 1]);
                bool here = (sd < bs[t])     || (sd == bs[t]     && id < bi[t]);
                bs[t] = up ? bs[t - 1] : (here ? sd : bs[t]);
                bi[t] = up ? bi[t - 1] : (here ? id : bi[t]);
            }
            bool top = (sd < bs[0]) || (sd == bs[0] && id < bi[0]);
            if (top) { bs[0] = sd; bi[0] = id; }
        }
    }

    float wsum = 0.0f, r = 0.0f, g2 = 0.0f, b2 = 0.0f;
#pragma unroll
    for (int j = 0; j < KTOP; ++j) {
        int id = bi[j];
        float d = sqrtf(fmaxf((float)bs[j], 0.0f));
        float w = expf(-0.1f * d) * sigm(opac[id]);
        wsum += w;
        r  += w * sigm(fdc[3 * id + 0]);
        g2 += w * sigm(fdc[3 * id + 1]);
        b2 += w * sigm(fdc[3 * id + 2]);
    }
    float inv = 1.0f / (wsum + 1e-8f);
    out[3 * ray + 0] = r  * inv;
    out[3 * ray + 1] = g2 * inv;
    out[3 * ray + 2] = b2 * inv;
}

// ---------------------------------------------------------------------------
extern "C" void kernel_launch(void* const* d_in, const int* in_sizes, int n_in,
                              void* d_out, int out_size, void* d_ws, size_t ws_size,
                              hipStream_t stream) {
    const float* rays_o = (const float*)d_in[0];
    const float* rays_d = (const float*)d_in[1];
    const float* xyz    = (const float*)d_in[2];
    const float* fdc    = (const float*)d_in[3];
    const float* opac   = (const float*)d_in[4];
    float* out = (float*)d_out;

    // ws: pm 1.57MB | theta 16KB | cnt 16KB | cand 4.19MB  (~5.8MB total)
    char* w = (char*)d_ws;
    float*  pm    = (float*)w;   w += (size_t)NPART * NRAYS * 4;
    float*  theta = (float*)w;   w += (size_t)NRAYS * 4;
    int*    cnt   = (int*)w;     w += (size_t)NRAYS * 4;
    float2* cand  = (float2*)w;

    theta_part_kernel<<<dim3(TBLK, RCT), 256, 0, stream>>>(xyz, rays_o, rays_d, pm);
    theta_reduce_kernel<<<NRAYS / 256, 256, 0, stream>>>(pm, theta, cnt);
    scan_kernel<<<dim3(SBLK, RCS), 256, 0, stream>>>(xyz, rays_o, rays_d, theta, cnt, cand);
    merge_kernel<<<NRAYS / 256, 256, 0, stream>>>(rays_o, rays_d, cnt, cand, xyz, fdc, opac, out);
}

// Round 5
// 240.129 us; speedup vs baseline: 4.2446x; 1.0177x over previous
//
#include <hip/hip_runtime.h>
#include <math.h>

#define NPTS   100000
#define NRAYS  4096
#define KTOP   10
#define KMER   12
#define CAP    128
#define LCAP   12

// scan: 16 pts/lane, blocks of 256 = 4096 pts/block, 25 blocks = 102400 padded
#define PSC    16
#define SBLK   25
#define RCS    64                 // ray chunks for scan
#define RPBS   (NRAYS / RCS)      // 64 rays per scan block

// theta sample: 8 pts/lane, 16 blocks of 2048 = 32768 pts, 64 parts of 512
#define PTH    8
#define TBLK   16
#define NPART  (TBLK * 4)
#define RCT    64                 // ray chunks for theta
#define RPBT   (NRAYS / RCT)      // 64 rays per theta block

static_assert(SBLK * 4096 >= NPTS, "scan covers all points");
static_assert(TBLK * 2048 <= NPTS, "theta sample within real points");

__device__ __forceinline__ float4 make_center(const float* __restrict__ ro,
                                              const float* __restrict__ rd,
                                              int ray, float w) {
    float ox = ro[3 * ray + 0], oy = ro[3 * ray + 1], oz = ro[3 * ray + 2];
    float dx = rd[3 * ray + 0], dy = rd[3 * ray + 1], dz = rd[3 * ray + 2];
    float cx, cy, cz;
    {
#pragma clang fp contract(off)
        cx = ox + dx * 3.0f;
        cy = oy + dy * 3.0f;
        cz = oz + dz * 3.0f;
    }
    return make_float4(cx, cy, cz, w);
}

// ---------------------------------------------------------------------------
// theta_part: points in VGPRs (8/lane, part = wave's 512 pts), ray centers in
// LDS, 4-ray-interleaved butterfly max -> pm[part][ray] (float4 store).
// ---------------------------------------------------------------------------
__global__ __launch_bounds__(256) void theta_part_kernel(const float* __restrict__ xyz,
                                                         const float* __restrict__ ro,
                                                         const float* __restrict__ rd,
                                                         float* __restrict__ pm) {
    __shared__ float4 rsh[RPBT];
    const int pblk = blockIdx.x, rchunk = blockIdx.y;
    const int tid = threadIdx.x, wave = tid >> 6, lane = tid & 63;
    const int rbase = rchunk * RPBT;

    if (tid < RPBT) rsh[tid] = make_center(ro, rd, rbase + tid, 0.0f);

    const int id0 = pblk * 2048 + wave * 512 + lane;   // < 32768, all real
    float px[PTH], py[PTH], pz[PTH], pw[PTH];
#pragma unroll
    for (int u = 0; u < PTH; ++u) {
        int id = id0 + u * 64;
        float x = xyz[3 * id + 0], y = xyz[3 * id + 1], z = xyz[3 * id + 2];
        px[u] = x; py[u] = y; pz[u] = z;
        pw[u] = -0.5f * fmaf(x, x, fmaf(y, y, z * z));
    }
    __syncthreads();

    const int part = pblk * 4 + wave;
    for (int r = 0; r < RPBT; r += 4) {
        float4 r0 = rsh[r], r1 = rsh[r + 1], r2 = rsh[r + 2], r3 = rsh[r + 3];
        float m0 = -INFINITY, m1 = -INFINITY, m2 = -INFINITY, m3 = -INFINITY;
#pragma unroll
        for (int u = 0; u < PTH; ++u) {
            float t0 = fmaf(pz[u], r0.z, pw[u]); t0 = fmaf(py[u], r0.y, t0); t0 = fmaf(px[u], r0.x, t0);
            m0 = fmaxf(m0, t0);
            float t1 = fmaf(pz[u], r1.z, pw[u]); t1 = fmaf(py[u], r1.y, t1); t1 = fmaf(px[u], r1.x, t1);
            m1 = fmaxf(m1, t1);
            float t2 = fmaf(pz[u], r2.z, pw[u]); t2 = fmaf(py[u], r2.y, t2); t2 = fmaf(px[u], r2.x, t2);
            m2 = fmaxf(m2, t2);
            float t3 = fmaf(pz[u], r3.z, pw[u]); t3 = fmaf(py[u], r3.y, t3); t3 = fmaf(px[u], r3.x, t3);
            m3 = fmaxf(m3, t3);
        }
#pragma unroll
        for (int off = 1; off < 64; off <<= 1) {       // 4 interleaved chains
            m0 = fmaxf(m0, __shfl_xor(m0, off));
            m1 = fmaxf(m1, __shfl_xor(m1, off));
            m2 = fmaxf(m2, __shfl_xor(m2, off));
            m3 = fmaxf(m3, __shfl_xor(m3, off));
        }
        if (lane == 0)
            *(float4*)&pm[part * NRAYS + rbase + r] = make_float4(m0, m1, m2, m3);
    }
}

// ---------------------------------------------------------------------------
// theta_reduce: theta[ray] = 10th-largest of 64 part maxima (guarantees >=10
// distinct points with score >= theta). Batched loads; zeroes cnt.
// ---------------------------------------------------------------------------
__global__ __launch_bounds__(256) void theta_reduce_kernel(const float* __restrict__ pm,
                                                           float* __restrict__ theta,
                                                           int* __restrict__ cnt) {
    const int ray = blockIdx.x * 256 + threadIdx.x;
    float vs[KTOP];
#pragma unroll
    for (int j = 0; j < KTOP; ++j) vs[j] = -INFINITY;
#pragma unroll 1
    for (int g = 0; g < NPART / 8; ++g) {
        float m[8];
#pragma unroll
        for (int j = 0; j < 8; ++j) m[j] = pm[(g * 8 + j) * NRAYS + ray];
#pragma unroll
        for (int j = 0; j < 8; ++j) {
            float v = m[j];
            if (v > vs[KTOP - 1]) {
#pragma unroll
                for (int s = KTOP - 1; s >= 1; --s) {
                    bool up = v > vs[s - 1], here = v > vs[s];
                    vs[s] = up ? vs[s - 1] : (here ? v : vs[s]);
                }
                if (v > vs[0]) vs[0] = v;
            }
        }
    }
    theta[ray] = vs[KTOP - 1];
    cnt[ray] = 0;
}

// ---------------------------------------------------------------------------
// scan: 16 pts/lane in VGPRs, rays+theta in LDS (2-ahead prefetch). Emit all
// points with score >= theta into per-ray LDS buffers (LDS atomics); one bulk
// global flush per block. Overflow (>LCAP per ray-block) -> direct global.
// ---------------------------------------------------------------------------
__global__ __launch_bounds__(256) void scan_kernel(const float* __restrict__ xyz,
                                                   const float* __restrict__ ro,
                                                   const float* __restrict__ rd,
                                                   const float* __restrict__ theta,
                                                   int* __restrict__ cnt,
                                                   float2* __restrict__ cand) {
    __shared__ float4 rsh[RPBS];
    __shared__ int    lcnt[RPBS];
    __shared__ float2 lbuf[RPBS][LCAP];
    const int pblk = blockIdx.x, rchunk = blockIdx.y;
    const int tid = threadIdx.x, wave = tid >> 6, lane = tid & 63;
    const int rbase = rchunk * RPBS;

    if (tid < RPBS) {
        rsh[tid] = make_center(ro, rd, rbase + tid, theta[rbase + tid]);
        lcnt[tid] = 0;
    }

    const int id0 = pblk * 4096 + wave * 1024 + lane;
    float px[PSC], py[PSC], pz[PSC], pw[PSC];
#pragma unroll
    for (int u = 0; u < PSC; ++u) {
        int id = id0 + u * 64;
        bool valid = (id < NPTS);
        int idc = valid ? id : 0;
        float x = xyz[3 * idc + 0], y = xyz[3 * idc + 1], z = xyz[3 * idc + 2];
        px[u] = x; py[u] = y; pz[u] = z;
        pw[u] = valid ? -0.5f * fmaf(x, x, fmaf(y, y, z * z)) : -INFINITY;
    }
    __syncthreads();

    float4 rp = rsh[0], rp1 = rsh[1];
    for (int r = 0; r < RPBS; ++r) {
        float4 rp2 = rsh[(r + 2) & (RPBS - 1)];        // 2-ahead prefetch
        float s[PSC];
#pragma unroll
        for (int u = 0; u < PSC; ++u) {
            float t = fmaf(pz[u], rp.z, pw[u]);
            t = fmaf(py[u], rp.y, t);
            t = fmaf(px[u], rp.x, t);
            s[u] = t;
        }
        float a0 = fmaxf(fmaxf(s[0], s[1]), s[2]);
        float a1 = fmaxf(fmaxf(s[3], s[4]), s[5]);
        float a2 = fmaxf(fmaxf(s[6], s[7]), s[8]);
        float a3 = fmaxf(fmaxf(s[9], s[10]), s[11]);
        float a4 = fmaxf(fmaxf(s[12], s[13]), s[14]);
        float b0 = fmaxf(fmaxf(a0, a1), a2);
        float b1 = fmaxf(fmaxf(a3, a4), s[15]);
        float hm = fmaxf(b0, b1);

        if (__ballot(hm >= rp.w)) {
#pragma unroll
            for (int u = 0; u < PSC; ++u) {
                if (s[u] >= rp.w) {
                    int slot = atomicAdd(&lcnt[r], 1);            // LDS atomic
                    float2 e = make_float2(s[u], __int_as_float(id0 + u * 64));
                    if (slot < LCAP) {
                        lbuf[r][slot] = e;
                    } else {                                      // ~never
                        int gs = atomicAdd(&cnt[rbase + r], 1);
                        if (gs < CAP) cand[((rbase + r) << 7) + gs] = e;
                    }
                }
            }
        }
        rp = rp1; rp1 = rp2;
    }

    __syncthreads();
    if (tid < RPBS) {                                  // bulk flush: 1 atomic/ray
        int n = lcnt[tid];
        n = n < LCAP ? n : LCAP;
        if (n > 0) {
            const int rayid = rbase + tid;
            int base = atomicAdd(&cnt[rayid], n);
            for (int j = 0; j < n; ++j) {
                int slot = base + j;
                if (slot < CAP) cand[(rayid << 7) + slot] = lbuf[tid][j];
            }
        }
    }
}

// ---------------------------------------------------------------------------
// merge: per ray top-12 by f32 score (idx tie-break), exact f64 re-rank ->
// final 10 -> weights + rgb. Batched candidate loads.
// ---------------------------------------------------------------------------
__device__ __forceinline__ float sigm(float x) { return 1.0f / (1.0f + expf(-x)); }

__global__ __launch_bounds__(256) void merge_kernel(const float* __restrict__ ro,
                                                    const float* __restrict__ rd,
                                                    const int* __restrict__ cnt,
                                                    const float2* __restrict__ cand,
                                                    const float* __restrict__ xyz,
                                                    const float* __restrict__ fdc,
                                                    const float* __restrict__ opac,
                                                    float* __restrict__ out) {
    const int ray = blockIdx.x * 256 + threadIdx.x;
    int n = cnt[ray];
    n = n < CAP ? n : CAP;
    int nm = n;
#pragma unroll
    for (int off = 1; off < 64; off <<= 1) {
        int o = __shfl_xor(nm, off);
        nm = nm > o ? nm : o;
    }

    float vs[KMER];
    int   vi[KMER];
#pragma unroll
    for (int j = 0; j < KMER; ++j) { vs[j] = -INFINITY; vi[j] = 0x7fffffff; }

    const float2* cl = cand + (ray << 7);
#pragma unroll 1
    for (int j0 = 0; j0 < nm; j0 += 8) {
        float2 e[8];
#pragma unroll
        for (int j = 0; j < 8; ++j) {
            int idx = j0 + j;
            e[j] = cl[idx < CAP ? idx : CAP - 1];
        }
#pragma unroll
        for (int j = 0; j < 8; ++j) {
            if (j0 + j < n) {
                float sc = e[j].x;
                int   id = __float_as_int(e[j].y);
                bool beat = (sc > vs[KMER - 1]) || (sc == vs[KMER - 1] && id < vi[KMER - 1]);
                if (beat) {
#pragma unroll
                    for (int t = KMER - 1; t >= 1; --t) {
                        bool up   = (sc > vs[t - 1]) || (sc == vs[t - 1] && id < vi[t - 1]);
                        bool here = (sc > vs[t])     || (sc == vs[t]     && id < vi[t]);
                        vs[t] = up ? vs[t - 1] : (here ? sc : vs[t]);
                        vi[t] = up ? vi[t - 1] : (here ? id : vi[t]);
                    }
                    bool top = (sc > vs[0]) || (sc == vs[0] && id < vi[0]);
                    if (top) { vs[0] = sc; vi[0] = id; }
                }
            }
        }
    }

    // exact f64 re-rank of the 12 survivors (invalid slots -> +inf)
    float ox = ro[3 * ray + 0], oy = ro[3 * ray + 1], oz = ro[3 * ray + 2];
    float dx = rd[3 * ray + 0], dy = rd[3 * ray + 1], dz = rd[3 * ray + 2];
    float cxf, cyf, czf;
    {
#pragma clang fp contract(off)
        cxf = ox + dx * 3.0f;
        cyf = oy + dy * 3.0f;
        czf = oz + dz * 3.0f;
    }
    double Cx = (double)cxf, Cy = (double)cyf, Cz = (double)czf;
    double cn = Cx * Cx + Cy * Cy + Cz * Cz;

    double sq[KMER];
#pragma unroll
    for (int j = 0; j < KMER; ++j) {
        int id = vi[j];
        bool valid = (id != 0x7fffffff);
        int idc = valid ? id : 0;
        double X = (double)xyz[3 * idc + 0];
        double Y = (double)xyz[3 * idc + 1];
        double Z = (double)xyz[3 * idc + 2];
        double v = cn + (X * X + Y * Y + Z * Z) - 2.0 * (Cx * X + Cy * Y + Cz * Z);
        sq[j] = valid ? v : (double)INFINITY;
    }

    double bs[KTOP];
    int    bi[KTOP];
#pragma unroll
    for (int j = 0; j < KTOP; ++j) { bs[j] = INFINITY; bi[j] = 0x7fffffff; }
#pragma unroll
    for (int j = 0; j < KMER; ++j) {
        double sd = sq[j];
        int    id = vi[j];
        bool beat = (sd < bs[KTOP - 1]) || (sd == bs[KTOP - 1] && id < bi[KTOP - 1]);
        if (beat) {
#pragma unroll
            for (int t = KTOP - 1; t >= 1; --t) {
                bool up   = (sd < bs[t - 1]) || (sd == bs[t - 1] && id < bi[t - 1]);
                bool here = (sd < bs[t])     || (sd == bs[t]     && id < bi[t]);
                bs[t] = up ? bs[t - 1] : (here ? sd : bs[t]);
                bi[t] = up ? bi[t - 1] : (here ? id : bi[t]);
            }
            bool top = (sd < bs[0]) || (sd == bs[0] && id < bi[0]);
            if (top) { bs[0] = sd; bi[0] = id; }
        }
    }

    float wsum = 0.0f, r = 0.0f, g2 = 0.0f, b2 = 0.0f;
#pragma unroll
    for (int j = 0; j < KTOP; ++j) {
        int id = bi[j];
        float d = sqrtf(fmaxf((float)bs[j], 0.0f));
        float w = expf(-0.1f * d) * sigm(opac[id]);
        wsum += w;
        r  += w * sigm(fdc[3 * id + 0]);
        g2 += w * sigm(fdc[3 * id + 1]);
        b2 += w * sigm(fdc[3 * id + 2]);
    }
    float inv = 1.0f / (wsum + 1e-8f);
    out[3 * ray + 0] = r  * inv;
    out[3 * ray + 1] = g2 * inv;
    out[3 * ray + 2] = b2 * inv;
}

// ---------------------------------------------------------------------------
extern "C" void kernel_launch(void* const* d_in, const int* in_sizes, int n_in,
                              void* d_out, int out_size, void* d_ws, size_t ws_size,
                              hipStream_t stream) {
    const float* rays_o = (const float*)d_in[0];
    const float* rays_d = (const float*)d_in[1];
    const float* xyz    = (const float*)d_in[2];
    const float* fdc    = (const float*)d_in[3];
    const float* opac   = (const float*)d_in[4];
    float* out = (float*)d_out;

    // ws: pm 1.0MB | theta 16KB | cnt 16KB | cand 4.0MB  (~5.1MB total)
    char* w = (char*)d_ws;
    float*  pm    = (float*)w;   w += (size_t)NPART * NRAYS * 4;
    float*  theta = (float*)w;   w += (size_t)NRAYS * 4;
    int*    cnt   = (int*)w;     w += (size_t)NRAYS * 4;
    float2* cand  = (float2*)w;

    theta_part_kernel<<<dim3(TBLK, RCT), 256, 0, stream>>>(xyz, rays_o, rays_d, pm);
    theta_reduce_kernel<<<NRAYS / 256, 256, 0, stream>>>(pm, theta, cnt);
    scan_kernel<<<dim3(SBLK, RCS), 256, 0, stream>>>(xyz, rays_o, rays_d, theta, cnt, cand);
    merge_kernel<<<NRAYS / 256, 256, 0, stream>>>(rays_o, rays_d, cnt, cand, xyz, fdc, opac, out);
}

// Round 6
// 180.726 us; speedup vs baseline: 5.6398x; 1.3287x over previous
//
#include <hip/hip_runtime.h>
#include <math.h>

#define NPTS   100000
#define NRAYS  4096
#define KTOP   10
#define KMER   12
#define CAP    128
#define LCAP   12

// scan: 16 pts/lane, blocks of 256 = 4096 pts/block, 25 blocks = 102400 padded
#define PSC    16
#define SBLK   25
#define RCS    64                 // ray chunks for scan
#define RPBS   (NRAYS / RCS)      // 64 rays per scan block

// theta sample: 8 pts/lane, 16 blocks of 2048 = 32768 pts, 64 parts of 512
#define PTH    8
#define TBLK   16
#define NPART  (TBLK * 4)
#define RCT    64                 // ray chunks for theta
#define RPBT   (NRAYS / RCT)      // 64 rays per theta block

static_assert(SBLK * 4096 >= NPTS, "scan covers all points");
static_assert(TBLK * 2048 <= NPTS, "theta sample within real points");

__device__ __forceinline__ float4 make_center(const float* __restrict__ ro,
                                              const float* __restrict__ rd,
                                              int ray, float w) {
    float ox = ro[3 * ray + 0], oy = ro[3 * ray + 1], oz = ro[3 * ray + 2];
    float dx = rd[3 * ray + 0], dy = rd[3 * ray + 1], dz = rd[3 * ray + 2];
    float cx, cy, cz;
    {
#pragma clang fp contract(off)
        cx = ox + dx * 3.0f;
        cy = oy + dy * 3.0f;
        cz = oz + dz * 3.0f;
    }
    return make_float4(cx, cy, cz, w);
}

// ---------------------------------------------------------------------------
// theta_part: points in VGPRs (8/lane, part = wave's 512 pts), ray centers in
// LDS, 4-ray-interleaved butterfly max -> pm[part][ray] (float4 store).
// ---------------------------------------------------------------------------
__global__ __launch_bounds__(256) void theta_part_kernel(const float* __restrict__ xyz,
                                                         const float* __restrict__ ro,
                                                         const float* __restrict__ rd,
                                                         float* __restrict__ pm) {
    __shared__ float4 rsh[RPBT];
    const int pblk = blockIdx.x, rchunk = blockIdx.y;
    const int tid = threadIdx.x, wave = tid >> 6, lane = tid & 63;
    const int rbase = rchunk * RPBT;

    if (tid < RPBT) rsh[tid] = make_center(ro, rd, rbase + tid, 0.0f);

    const int id0 = pblk * 2048 + wave * 512 + lane;   // < 32768, all real
    float px[PTH], py[PTH], pz[PTH], pw[PTH];
#pragma unroll
    for (int u = 0; u < PTH; ++u) {
        int id = id0 + u * 64;
        float x = xyz[3 * id + 0], y = xyz[3 * id + 1], z = xyz[3 * id + 2];
        px[u] = x; py[u] = y; pz[u] = z;
        pw[u] = -0.5f * fmaf(x, x, fmaf(y, y, z * z));
    }
    __syncthreads();

    const int part = pblk * 4 + wave;
    for (int r = 0; r < RPBT; r += 4) {
        float4 r0 = rsh[r], r1 = rsh[r + 1], r2 = rsh[r + 2], r3 = rsh[r + 3];
        float m0 = -INFINITY, m1 = -INFINITY, m2 = -INFINITY, m3 = -INFINITY;
#pragma unroll
        for (int u = 0; u < PTH; ++u) {
            float t0 = fmaf(pz[u], r0.z, pw[u]); t0 = fmaf(py[u], r0.y, t0); t0 = fmaf(px[u], r0.x, t0);
            m0 = fmaxf(m0, t0);
            float t1 = fmaf(pz[u], r1.z, pw[u]); t1 = fmaf(py[u], r1.y, t1); t1 = fmaf(px[u], r1.x, t1);
            m1 = fmaxf(m1, t1);
            float t2 = fmaf(pz[u], r2.z, pw[u]); t2 = fmaf(py[u], r2.y, t2); t2 = fmaf(px[u], r2.x, t2);
            m2 = fmaxf(m2, t2);
            float t3 = fmaf(pz[u], r3.z, pw[u]); t3 = fmaf(py[u], r3.y, t3); t3 = fmaf(px[u], r3.x, t3);
            m3 = fmaxf(m3, t3);
        }
#pragma unroll
        for (int off = 1; off < 64; off <<= 1) {       // 4 interleaved chains
            m0 = fmaxf(m0, __shfl_xor(m0, off));
            m1 = fmaxf(m1, __shfl_xor(m1, off));
            m2 = fmaxf(m2, __shfl_xor(m2, off));
            m3 = fmaxf(m3, __shfl_xor(m3, off));
        }
        if (lane == 0)
            *(float4*)&pm[part * NRAYS + rbase + r] = make_float4(m0, m1, m2, m3);
    }
}

// ---------------------------------------------------------------------------
// theta_reduce: theta[ray] = 10th-largest of 64 part maxima (guarantees >=10
// distinct points with score >= theta). Batched loads; zeroes cnt.
// ---------------------------------------------------------------------------
__global__ __launch_bounds__(256) void theta_reduce_kernel(const float* __restrict__ pm,
                                                           float* __restrict__ theta,
                                                           int* __restrict__ cnt) {
    const int ray = blockIdx.x * 256 + threadIdx.x;
    float vs[KTOP];
#pragma unroll
    for (int j = 0; j < KTOP; ++j) vs[j] = -INFINITY;
#pragma unroll 1
    for (int g = 0; g < NPART / 8; ++g) {
        float m[8];
#pragma unroll
        for (int j = 0; j < 8; ++j) m[j] = pm[(g * 8 + j) * NRAYS + ray];
#pragma unroll
        for (int j = 0; j < 8; ++j) {
            float v = m[j];
            if (v > vs[KTOP - 1]) {
#pragma unroll
                for (int s = KTOP - 1; s >= 1; --s) {
                    bool up = v > vs[s - 1], here = v > vs[s];
                    vs[s] = up ? vs[s - 1] : (here ? v : vs[s]);
                }
                if (v > vs[0]) vs[0] = v;
            }
        }
    }
    theta[ray] = vs[KTOP - 1];
    cnt[ray] = 0;
}

// ---------------------------------------------------------------------------
// scan: 16 pts/lane in VGPRs, rays+theta in LDS (2-ahead prefetch). Emit all
// points with score >= theta into per-ray LDS buffers (LDS atomics); one bulk
// global flush per block. Overflow (>LCAP per ray-block) -> direct global.
// ---------------------------------------------------------------------------
__global__ __launch_bounds__(256) void scan_kernel(const float* __restrict__ xyz,
                                                   const float* __restrict__ ro,
                                                   const float* __restrict__ rd,
                                                   const float* __restrict__ theta,
                                                   int* __restrict__ cnt,
                                                   float2* __restrict__ cand) {
    __shared__ float4 rsh[RPBS];
    __shared__ int    lcnt[RPBS];
    __shared__ float2 lbuf[RPBS][LCAP];
    const int pblk = blockIdx.x, rchunk = blockIdx.y;
    const int tid = threadIdx.x, wave = tid >> 6, lane = tid & 63;
    const int rbase = rchunk * RPBS;

    if (tid < RPBS) {
        rsh[tid] = make_center(ro, rd, rbase + tid, theta[rbase + tid]);
        lcnt[tid] = 0;
    }

    const int id0 = pblk * 4096 + wave * 1024 + lane;
    float px[PSC], py[PSC], pz[PSC], pw[PSC];
#pragma unroll
    for (int u = 0; u < PSC; ++u) {
        int id = id0 + u * 64;
        bool valid = (id < NPTS);
        int idc = valid ? id : 0;
        float x = xyz[3 * idc + 0], y = xyz[3 * idc + 1], z = xyz[3 * idc + 2];
        px[u] = x; py[u] = y; pz[u] = z;
        pw[u] = valid ? -0.5f * fmaf(x, x, fmaf(y, y, z * z)) : -INFINITY;
    }
    __syncthreads();

    float4 rp = rsh[0], rp1 = rsh[1];
    for (int r = 0; r < RPBS; ++r) {
        float4 rp2 = rsh[(r + 2) & (RPBS - 1)];        // 2-ahead prefetch
        float s[PSC];
#pragma unroll
        for (int u = 0; u < PSC; ++u) {
            float t = fmaf(pz[u], rp.z, pw[u]);
            t = fmaf(py[u], rp.y, t);
            t = fmaf(px[u], rp.x, t);
            s[u] = t;
        }
        float a0 = fmaxf(fmaxf(s[0], s[1]), s[2]);
        float a1 = fmaxf(fmaxf(s[3], s[4]), s[5]);
        float a2 = fmaxf(fmaxf(s[6], s[7]), s[8]);
        float a3 = fmaxf(fmaxf(s[9], s[10]), s[11]);
        float a4 = fmaxf(fmaxf(s[12], s[13]), s[14]);
        float b0 = fmaxf(fmaxf(a0, a1), a2);
        float b1 = fmaxf(fmaxf(a3, a4), s[15]);
        float hm = fmaxf(b0, b1);

        if (__ballot(hm >= rp.w)) {
#pragma unroll
            for (int u = 0; u < PSC; ++u) {
                if (s[u] >= rp.w) {
                    int slot = atomicAdd(&lcnt[r], 1);            // LDS atomic
                    float2 e = make_float2(s[u], __int_as_float(id0 + u * 64));
                    if (slot < LCAP) {
                        lbuf[r][slot] = e;
                    } else {                                      // ~never
                        int gs = atomicAdd(&cnt[rbase + r], 1);
                        if (gs < CAP) cand[((rbase + r) << 7) + gs] = e;
                    }
                }
            }
        }
        rp = rp1; rp1 = rp2;
    }

    __syncthreads();
    if (tid < RPBS) {                                  // bulk flush: 1 atomic/ray
        int n = lcnt[tid];
        n = n < LCAP ? n : LCAP;
        if (n > 0) {
            const int rayid = rbase + tid;
            int base = atomicAdd(&cnt[rayid], n);
            for (int j = 0; j < n; ++j) {
                int slot = base + j;
                if (slot < CAP) cand[(rayid << 7) + slot] = lbuf[tid][j];
            }
        }
    }
}

// ---------------------------------------------------------------------------
// merge: WAVE PER RAY. Coalesced candidate load (2 slots/lane), top-12 via 12
// wave-argmax rounds on packed (score desc, id asc) u64 keys, parallel f64
// re-rank across 12 lanes, rank-count -> 10 smallest, butterfly-sum rgb.
// ---------------------------------------------------------------------------
__device__ __forceinline__ float sigm(float x) { return 1.0f / (1.0f + expf(-x)); }

__device__ __forceinline__ unsigned long long mkkey(float sc, int id, bool v) {
    unsigned u = __float_as_uint(sc);
    u = (u & 0x80000000u) ? ~u : (u | 0x80000000u);    // order-preserving f32->u32
    unsigned long long k = ((unsigned long long)u << 32) | (unsigned)(~id);
    return v ? k : 0ull;                               // smaller id -> larger key
}

__global__ __launch_bounds__(256) void merge_kernel(const float* __restrict__ ro,
                                                    const float* __restrict__ rd,
                                                    const int* __restrict__ cnt,
                                                    const float2* __restrict__ cand,
                                                    const float* __restrict__ xyz,
                                                    const float* __restrict__ fdc,
                                                    const float* __restrict__ opac,
                                                    float* __restrict__ out) {
    const int wave = threadIdx.x >> 6, lane = threadIdx.x & 63;
    const int ray = blockIdx.x * 4 + wave;

    int n = cnt[ray];
    n = n < CAP ? n : CAP;

    const float2* cl = cand + (ray << 7);
    float2 e0 = cl[lane];                              // coalesced 512B wave-load
    float2 e1 = cl[64 + lane];
    int id0 = __float_as_int(e0.y), id1 = __float_as_int(e1.y);

    unsigned long long k0 = mkkey(e0.x, id0, lane < n);
    unsigned long long k1 = mkkey(e1.x, id1, lane + 64 < n);

    int sel = -1;                                      // lane j ends holding j-th best id
    unsigned long long kl = k0 > k1 ? k0 : k1;
#pragma unroll
    for (int j = 0; j < KMER; ++j) {
        unsigned long long m = kl;
#pragma unroll
        for (int off = 1; off < 64; off <<= 1) {
            unsigned long long o = __shfl_xor(m, off);
            m = m > o ? m : o;
        }
        bool win = (kl == m) && (m != 0ull);
        int wid = (k0 >= k1) ? id0 : id1;              // winner's id on winner lane
        unsigned long long wmask = __ballot(win);
        int wl = __ffsll(wmask) - 1;                   // unique winner (keys unique)
        int bid = __shfl(wid, wl & 63);
        if (m == 0ull) bid = -1;
        if (lane == j) sel = bid;
        if (win) {                                     // mask out the winner
            if (k0 >= k1) k0 = 0ull; else k1 = 0ull;
            kl = k0 > k1 ? k0 : k1;
        }
    }

    // exact f64 re-rank across lanes 0..11 (parallel gathers)
    float ox = ro[3 * ray + 0], oy = ro[3 * ray + 1], oz = ro[3 * ray + 2];
    float dx = rd[3 * ray + 0], dy = rd[3 * ray + 1], dz = rd[3 * ray + 2];
    float cxf, cyf, czf;
    {
#pragma clang fp contract(off)
        cxf = ox + dx * 3.0f;
        cyf = oy + dy * 3.0f;
        czf = oz + dz * 3.0f;
    }
    double Cx = (double)cxf, Cy = (double)cyf, Cz = (double)czf;
    double cn = Cx * Cx + Cy * Cy + Cz * Cz;

    bool valid = (lane < KMER) && (sel >= 0);
    int pid = valid ? sel : 0;
    double X = (double)xyz[3 * pid + 0];
    double Y = (double)xyz[3 * pid + 1];
    double Z = (double)xyz[3 * pid + 2];
    double sq = valid ? (cn + (X * X + Y * Y + Z * Z) - 2.0 * (Cx * X + Cy * Y + Cz * Z))
                      : (double)INFINITY;
    int cid = valid ? sel : 0x7fffffff;

    int rank = 0;
#pragma unroll
    for (int k = 0; k < KMER; ++k) {                   // rank among the 12
        double sk = __shfl(sq, k);
        int    ik = __shfl(cid, k);
        if ((sk < sq) || (sk == sq && ik < cid)) ++rank;
    }

    bool take = valid && (rank < KTOP);
    float w = 0.0f, rr = 0.0f, gg = 0.0f, bb = 0.0f;
    if (take) {                                        // parallel gathers, 10 lanes
        float dd = sqrtf(fmaxf((float)sq, 0.0f));
        w  = expf(-0.1f * dd) * sigm(opac[pid]);
        rr = w * sigm(fdc[3 * pid + 0]);
        gg = w * sigm(fdc[3 * pid + 1]);
        bb = w * sigm(fdc[3 * pid + 2]);
    }
#pragma unroll
    for (int off = 1; off < 64; off <<= 1) {
        w  += __shfl_xor(w,  off);
        rr += __shfl_xor(rr, off);
        gg += __shfl_xor(gg, off);
        bb += __shfl_xor(bb, off);
    }
    if (lane == 0) {
        float inv = 1.0f / (w + 1e-8f);
        out[3 * ray + 0] = rr * inv;
        out[3 * ray + 1] = gg * inv;
        out[3 * ray + 2] = bb * inv;
    }
}

// ---------------------------------------------------------------------------
extern "C" void kernel_launch(void* const* d_in, const int* in_sizes, int n_in,
                              void* d_out, int out_size, void* d_ws, size_t ws_size,
                              hipStream_t stream) {
    const float* rays_o = (const float*)d_in[0];
    const float* rays_d = (const float*)d_in[1];
    const float* xyz    = (const float*)d_in[2];
    const float* fdc    = (const float*)d_in[3];
    const float* opac   = (const float*)d_in[4];
    float* out = (float*)d_out;

    // ws: pm 1.0MB | theta 16KB | cnt 16KB | cand 4.0MB  (~5.1MB total)
    char* w = (char*)d_ws;
    float*  pm    = (float*)w;   w += (size_t)NPART * NRAYS * 4;
    float*  theta = (float*)w;   w += (size_t)NRAYS * 4;
    int*    cnt   = (int*)w;     w += (size_t)NRAYS * 4;
    float2* cand  = (float2*)w;

    theta_part_kernel<<<dim3(TBLK, RCT), 256, 0, stream>>>(xyz, rays_o, rays_d, pm);
    theta_reduce_kernel<<<NRAYS / 256, 256, 0, stream>>>(pm, theta, cnt);
    scan_kernel<<<dim3(SBLK, RCS), 256, 0, stream>>>(xyz, rays_o, rays_d, theta, cnt, cand);
    merge_kernel<<<NRAYS / 4, 256, 0, stream>>>(rays_o, rays_d, cnt, cand, xyz, fdc, opac, out);
}